// Round 15
// baseline (122.854 us; speedup 1.0000x reference)
//
#include <hip/hip_runtime.h>
#include <math.h>

#define Wd 256
#define Hd 256
#define KW 11
#define OUT_R 26              // output rows per block; stream 36 = 3 chunks of 12
#define RING 12               // ring size 12: slot=(2*jp+c)%12, chunk-independent
#define BLOCK 256

typedef float v2f __attribute__((ext_vector_type(2)));

__device__ __forceinline__ float rfl(float v) {
    return __int_as_float(__builtin_amdgcn_readfirstlane(__float_as_int(v)));
}

// Packed dual FP32 FMA via the COMPILER (not inline asm): llvm.fma.v2f32 is
// selected as v_pk_fma_f32 on gfx950 (HasPackedFP32Ops, double-rate fp32).
// R9 proved the packing itself executes at full rate (VALUBusy 40->27% at
// half the inst count) but asm operands serialized the 11-deep accumulator
// chains (19.6 cyc/inst effective). Builtin form leaves scheduling free.
// Numerics: HIP compiles -ffp-contract=fast, so the old `acc += w*x` was
// already fma -- explicit fma is bit-identical (absmax=0 preserved).
__device__ __forceinline__ v2f pkfma(v2f x, float w, v2f acc) {
    v2f wv; wv.x = w; wv.y = w;
    return __builtin_elementwise_fma(x, wv, acc);
}

// lgkmcnt-only barrier (R2/R5): LDS handoff without draining global prefetch.
__device__ __forceinline__ void barrier_lds_only() {
    asm volatile("s_waitcnt lgkmcnt(0)\n\ts_barrier" ::: "memory");
}

// R15: R5 body (best measured: 42.2us dispatch) + compiler-packed v2f FMA.
//
// Ledger (~42us invariant): barrier flavor/count (R2/R12), residency supply
// both directions (R4 worse, R14 neutral), prefetch depth (R5 -4%), skew
// (R6), step size (R7), LDS traffic -42% (R7: neutral!), bank conflicts,
// memory residency (L3==HBM), wave privatization (R10), atomics (R11),
// setprio (R13: -60%). The one variable tracking duration across ALL
// rounds: total VALU instruction count (R4 +27% inst -> +20% time;
// VALU-conserving restructures all neutral; R9 halved inst and halved
// VALUBusy -- packing works -- but asm dep-chains tripled cyc/inst).
// This round: halve the FMA stream with compiler-scheduled v_pk_fma_f32.
__global__ __launch_bounds__(BLOCK, 4) void ssim_pair_kernel(
    const float* __restrict__ img1, const float* __restrict__ img2,
    const float* __restrict__ window, float* __restrict__ out, float scale)
{
    __shared__ __align__(16) float4 rbE[2][2][136];
    __shared__ __align__(16) float4 rbO[2][2][136];   // 17.4 KB
    __shared__ float red[BLOCK / 64];

    const float C1 = 1e-4f, C2 = 9e-4f;
    const int t = threadIdx.x;
    const int band = blockIdx.x;     // 0..9 (band 9 partial: 22 rows)
    const int plane = blockIdx.y;    // 0..143
    const float* __restrict__ p1 = img1 + (size_t)plane * (Hd * Wd);
    const float* __restrict__ p2 = img2 + (size_t)plane * (Hd * Wd);

    // Separable 1D weights (win2d = a outer a, sum a = 1); pin to SGPRs.
    float wl[KW];
    {
        float c = sqrtf(window[5 * KW + 5]);
        #pragma unroll
        for (int k = 0; k < KW; ++k)
            wl[k] = rfl(window[k * KW + 5] / c);
    }

    // Zero the column-halo cells once (never written by the row pass).
    if (t < 4) {
        int buf = t >> 1, row = t & 1;
        float4 z = make_float4(0.f, 0.f, 0.f, 0.f);
        rbE[buf][row][0] = z; rbE[buf][row][1] = z;
        rbE[buf][row][130] = z; rbE[buf][row][131] = z; rbE[buf][row][132] = z;
        rbO[buf][row][0] = z; rbO[buf][row][1] = z; rbO[buf][row][2] = z;
        rbO[buf][row][131] = z; rbO[buf][row][132] = z;
    }

    const int ghbase = band * OUT_R - 5;   // global row of stream index 0

    v2f rXY[RING], rQP[RING];
    float acc = 0.f;

    // 2-deep prefetch pipeline (R5): cur = this step's pair, nxt = next.
    float cx0, cy0, cx1, cy1;
    float nx0, ny0, nx1, ny1;
    {
        int g0 = ghbase, g1 = ghbase + 1;
        cx0 = ((unsigned)g0 < (unsigned)Hd) ? p1[(g0 << 8) + t] : 0.f;
        cy0 = ((unsigned)g0 < (unsigned)Hd) ? p2[(g0 << 8) + t] : 0.f;
        cx1 = ((unsigned)g1 < (unsigned)Hd) ? p1[(g1 << 8) + t] : 0.f;
        cy1 = ((unsigned)g1 < (unsigned)Hd) ? p2[(g1 << 8) + t] : 0.f;
        int g2 = ghbase + 2, g3 = ghbase + 3;
        nx0 = ((unsigned)g2 < (unsigned)Hd) ? p1[(g2 << 8) + t] : 0.f;
        ny0 = ((unsigned)g2 < (unsigned)Hd) ? p2[(g2 << 8) + t] : 0.f;
        nx1 = ((unsigned)g3 < (unsigned)Hd) ? p1[(g3 << 8) + t] : 0.f;
        ny1 = ((unsigned)g3 < (unsigned)Hd) ? p2[(g3 << 8) + t] : 0.f;
    }

    #pragma unroll 1
    for (int ch = 0; ch < 3; ++ch) {
        #pragma unroll
        for (int jp = 0; jp < 6; ++jp) {
            const int i0 = 12 * ch + 2 * jp;        // uniform (ch runtime)
            const int s0 = (2 * jp) % RING;         // STATIC slot
            const int s1 = (2 * jp + 1) % RING;     // STATIC slot

            // ring insert rows i0, i0+1 (consume cur; out-of-range = zeros)
            {
                v2f v; v.x = cx0; v.y = cy0; rXY[s0] = v;
                v2f q; q.x = fmaf(cx0, cx0, cy0 * cy0); q.y = cx0 * cy0; rQP[s0] = q;
                v2f v2; v2.x = cx1; v2.y = cy1; rXY[s1] = v2;
                v2f q2; q2.x = fmaf(cx1, cx1, cy1 * cy1); q2.y = cx1 * cy1; rQP[s1] = q2;
            }
            // rotate pipeline, issue loads 2 steps ahead
            cx0 = nx0; cy0 = ny0; cx1 = nx1; cy1 = ny1;
            if (i0 + 4 < 36) {
                int g0 = ghbase + i0 + 4, g1 = ghbase + i0 + 5;
                nx0 = ((unsigned)g0 < (unsigned)Hd) ? p1[(g0 << 8) + t] : 0.f;
                ny0 = ((unsigned)g0 < (unsigned)Hd) ? p2[(g0 << 8) + t] : 0.f;
                nx1 = ((unsigned)g1 < (unsigned)Hd) ? p1[(g1 << 8) + t] : 0.f;
                ny1 = ((unsigned)g1 < (unsigned)Hd) ? p2[(g1 << 8) + t] : 0.f;
            }

            const int orow0 = band * OUT_R + i0 - 10;     // uniform
            if (i0 >= 10 && orow0 < Hd) {   // emit rows i0, i0+1
                const int buf = jp & 1;
                // vertical 11-tap conv: packed FMA, 4 v2f accumulators
                v2f vAB0, vQP0, vAB1, vQP1;
                vAB0.x = vAB0.y = vQP0.x = vQP0.y = 0.f;
                vAB1.x = vAB1.y = vQP1.x = vQP1.y = 0.f;
                #pragma unroll
                for (int m = 0; m < KW; ++m) {
                    const int sa = (2 * jp + 2 + m) % RING;
                    const int sb = (2 * jp + 3 + m) % RING;
                    float w = wl[m];
                    vAB0 = pkfma(rXY[sa], w, vAB0);  vQP0 = pkfma(rQP[sa], w, vQP0);
                    vAB1 = pkfma(rXY[sb], w, vAB1);  vQP1 = pkfma(rQP[sb], w, vQP1);
                }
                const int half = t >> 1;
                if (t & 1) {
                    rbO[buf][0][half + 3] = make_float4(vAB0.x, vAB0.y, vQP0.x, vQP0.y);
                    rbO[buf][1][half + 3] = make_float4(vAB1.x, vAB1.y, vQP1.x, vQP1.y);
                } else {
                    rbE[buf][0][half + 2] = make_float4(vAB0.x, vAB0.y, vQP0.x, vQP0.y);
                    rbE[buf][1][half + 2] = make_float4(vAB1.x, vAB1.y, vQP1.x, vQP1.y);
                }
                barrier_lds_only();   // loads stay in flight

                // horizontal 11-tap: packed FMA, 8 v2f accumulators
                const int r = t >> 7, cp = t & 127;   // output cols 2cp, 2cp+1
                const float4* bE = &rbE[buf][r][cp];
                const float4* bO = &rbO[buf][r][cp];
                v2f a0, q0, a1, q1;
                a0.x = a0.y = q0.x = q0.y = 0.f;
                a1.x = a1.y = q1.x = q1.y = 0.f;
                #pragma unroll
                for (int k = 0; k < 6; ++k) {
                    float4 vO = bO[k];                 // ds_read_b128
                    v2f oab; oab.x = vO.x; oab.y = vO.y;
                    v2f oqp; oqp.x = vO.z; oqp.y = vO.w;
                    a0 = pkfma(oab, wl[2 * k], a0);  q0 = pkfma(oqp, wl[2 * k], q0);
                    if (k >= 1) {
                        a1 = pkfma(oab, wl[2 * k - 1], a1);
                        q1 = pkfma(oqp, wl[2 * k - 1], q1);
                    }
                    float4 vE = bE[k];                 // ds_read_b128
                    v2f eab; eab.x = vE.x; eab.y = vE.y;
                    v2f eqp; eqp.x = vE.z; eqp.y = vE.w;
                    a1 = pkfma(eab, wl[2 * k], a1);  q1 = pkfma(eqp, wl[2 * k], q1);
                    if (k <= 4) {
                        a0 = pkfma(eab, wl[2 * k + 1], a0);
                        q0 = pkfma(eqp, wl[2 * k + 1], q0);
                    }
                }
                {
                    float mu1 = a0.x, mu2 = a0.y, sq = q0.x, sp = q0.y;
                    float mu12 = mu1 * mu2;
                    float musum = mu1 * mu1 + mu2 * mu2;
                    float num = (2.f * mu12 + C1) * (2.f * (sp - mu12) + C2);
                    float den = (musum + C1) * ((sq - musum) + C2);
                    acc += num * __builtin_amdgcn_rcpf(den);
                }
                {
                    float mu1 = a1.x, mu2 = a1.y, sq = q1.x, sp = q1.y;
                    float mu12 = mu1 * mu2;
                    float musum = mu1 * mu1 + mu2 * mu2;
                    float num = (2.f * mu12 + C1) * (2.f * (sp - mu12) + C2);
                    float den = (musum + C1) * ((sq - musum) + C2);
                    acc += num * __builtin_amdgcn_rcpf(den);
                }
            }
        }
    }

    // --- block reduction + fused global reduce (atomic; proven innocent R11) ---
    #pragma unroll
    for (int off = 32; off > 0; off >>= 1)
        acc += __shfl_down(acc, off, 64);
    int wave = t >> 6;
    if ((t & 63) == 0) red[wave] = acc;
    barrier_lds_only();
    if (t == 0) {
        float partial = red[0] + red[1] + red[2] + red[3];
        float v = partial * scale;                 // scale = -1/count
        if (band == 0 && plane == 0) v += 1.0f;    // out = 1 - sum/count
        atomicAdd(out, v);
    }
}

extern "C" void kernel_launch(void* const* d_in, const int* in_sizes, int n_in,
                              void* d_out, int out_size, void* d_ws, size_t ws_size,
                              hipStream_t stream) {
    const float* img1   = (const float*)d_in[0];
    const float* img2   = (const float*)d_in[1];
    const float* window = (const float*)d_in[2];
    float* out = (float*)d_out;

    const int planes = 16 * 9;                     // 144
    const int bands = (Hd + OUT_R - 1) / OUT_R;    // 10 (last band 22 rows)

    hipMemsetAsync(out, 0, sizeof(float), stream);

    const float scale = -(float)(1.0 / ((double)planes * Hd * Wd));
    dim3 grid(bands, planes);
    ssim_pair_kernel<<<grid, BLOCK, 0, stream>>>(img1, img2, window, out, scale);
}